// Round 7
// baseline (445.129 us; speedup 1.0000x reference)
//
#include <hip/hip_runtime.h>
#include <math.h>

#define N_NODES  100000
#define N_FEAT   128
#define N_HID    64
#define N_CLASS  10
#define N_GRAPHS 1000
#define N_EDGES  1600000
#define NTILES   1563      // ceil(100000/64)   (pre role, 64-node tiles)
#define BLK_N    128       // gather_mlp tile
#define NT2      782       // ceil(100000/128)
#define HF_GROUPS 8        // concurrent dst ranges
#define HF_RANGE 12500     // 100000/8; csr window 3.2 MB
#define HF_BLOCKS 2048     // hist-role block count
#define HF_GSZ   65536     // (HF_BLOCKS/8)*256 threads per range group
#define FUSED_BLOCKS (2*NTILES + (HF_BLOCKS - NTILES))   // 3611
#define CSR_STRIDE 64      // fixed bucket per node; P(deg>=64)~1e-20 @ Poisson(16)
#define EMAX_LDS 32        // staged slots per node; P(deg>32)~1e-4 -> global tail

typedef int iv4 __attribute__((ext_vector_type(4)));  // true vector type for nontemporal builtin

// ---- bf16 helpers: h stored bf16 (row = 128 B); all arithmetic fp32.
__device__ __forceinline__ float bflo(unsigned u) { return __uint_as_float(u << 16); }
__device__ __forceinline__ float bfhi(unsigned u) { return __uint_as_float(u & 0xffff0000u); }
__device__ __forceinline__ unsigned bf_rne(float f) {
    unsigned u = __float_as_uint(f);
    return (u + 0x7fffu + ((u >> 16) & 1u)) >> 16;
}
__device__ __forceinline__ unsigned pack2(float a, float b) {
    return bf_rne(a) | (bf_rne(b) << 16);
}

// ---- fused pre + hist (v6): pre (compute-bound GEMM) and hist (atomic-
// latency-bound, VALU 4% / HBM 22%) are independent; running them serially
// wasted ~25-35us of machine-idle time. Block-role split, even/odd
// interleaved so both roles start at t=0 on every CU:
//   bi < 3126: even -> pre tile bi/2 (1563), odd -> hist block bi/2 (1563)
//   bi >= 3126: hist blocks 1563..2047 (485)
// Unified-allocation tax: pre's 34.8 KB LDS + ~80 VGPR cap the fused kernel
// at 4 blocks/CU (16 waves) -- hist standalone ran ~25 waves/CU, but hist is
// occupancy-insensitive (33% occ -> 86us, 77% -> 79us), so the stretch is
// small vs the ~30us of pre fully hidden.
// hist body = v3 (best measured, 76.5us): 8 concurrent dst-ranges, NT
// dst+src reads. v4 lesson (705us!): never concentrate the 1.6M returning
// atomics onto few cache lines; keep them spread over 100K deg addresses.
// v0-v3 all 77-86us regardless of write pattern -> returning-atomic
// throughput floor (~10/cycle chip-wide), not write-bound.
__global__ __launch_bounds__(256, 4) void pre_hist_kernel(
    const float* __restrict__ x, const float* __restrict__ W,
    const float* __restrict__ b, uint2* __restrict__ h,
    const int* __restrict__ ei, int* __restrict__ deg, int* __restrict__ csr)
{
    __shared__ float xs[64][68];
    __shared__ float ws[64][68];
    const int bi = blockIdx.x;
    const int tid = threadIdx.x;

    int prei = -1, hb = -1;
    if (bi < 2 * NTILES) {
        if ((bi & 1) == 0) prei = bi >> 1;
        else hb = bi >> 1;
    } else {
        hb = NTILES + (bi - 2 * NTILES);
    }

    if (prei >= 0) {
        // ======== pre role: h0 = x @ pre_w + pre_b (bf16 out) ========
        const int tx = tid & 15, ty = tid >> 4;
        const int n0 = prei * 64;

        float acc[4][4];
#pragma unroll
        for (int i = 0; i < 4; ++i)
#pragma unroll
            for (int j = 0; j < 4; ++j) acc[i][j] = 0.f;

        for (int p = 0; p < 2; ++p) {
            __syncthreads();
#pragma unroll
            for (int t = 0; t < 4; ++t) {
                const int idx = t * 256 + tid;
                const int m = idx >> 4, kv = idx & 15;
                float4 v = make_float4(0.f, 0.f, 0.f, 0.f);
                if (n0 + m < N_NODES)
                    v = *(const float4*)(x + (size_t)(n0 + m) * N_FEAT + p * 64 + kv * 4);
                *(float4*)&xs[m][kv * 4] = v;
                *(float4*)&ws[m][kv * 4] =
                    *(const float4*)(W + (size_t)(p * 64 + m) * N_HID + kv * 4);
            }
            __syncthreads();
#pragma unroll 2
            for (int k4 = 0; k4 < 16; ++k4) {
                float4 a[4], bb[4];
#pragma unroll
                for (int i = 0; i < 4; ++i)
                    a[i] = *(const float4*)&xs[ty + 16 * i][k4 * 4];
#pragma unroll
                for (int j = 0; j < 4; ++j)
                    bb[j] = *(const float4*)&ws[k4 * 4 + j][tx * 4];
#pragma unroll
                for (int i = 0; i < 4; ++i) {
                    const float* ap = (const float*)&a[i];
#pragma unroll
                    for (int j = 0; j < 4; ++j) {
                        const float* bp = (const float*)&bb[j];
#pragma unroll
                        for (int c = 0; c < 4; ++c)
                            acc[i][c] = fmaf(ap[j], bp[c], acc[i][c]);
                    }
                }
            }
        }

        const float4 bias = *(const float4*)(b + tx * 4);
#pragma unroll
        for (int i = 0; i < 4; ++i) {
            const int node = n0 + ty + 16 * i;
            if (node < N_NODES) {
                h[(size_t)node * 16 + tx] = make_uint2(
                    pack2(acc[i][0] + bias.x, acc[i][1] + bias.y),
                    pack2(acc[i][2] + bias.z, acc[i][3] + bias.w));
            }
        }
    } else {
        // ======== hist role: fixed-stride CSR fill (v3 body) ========
        const int r   = hb & (HF_GROUPS - 1);
        const int g   = hb >> 3;
        const int lo  = r * HF_RANGE;
        const int hi  = lo + HF_RANGE;
        const int t0  = g * 256 + tid;
        const iv4* dst4 = (const iv4*)(ei + N_EDGES);
        for (int q = t0; q < N_EDGES / 4; q += HF_GSZ) {
            const iv4 d = __builtin_nontemporal_load(dst4 + q);
            const int e0 = q * 4;
            if (d.x >= lo && d.x < hi) {
                int p = atomicAdd(&deg[d.x], 1);
                if (p < CSR_STRIDE)
                    csr[d.x * CSR_STRIDE + p] = __builtin_nontemporal_load(ei + e0);
            }
            if (d.y >= lo && d.y < hi) {
                int p = atomicAdd(&deg[d.y], 1);
                if (p < CSR_STRIDE)
                    csr[d.y * CSR_STRIDE + p] = __builtin_nontemporal_load(ei + e0 + 1);
            }
            if (d.z >= lo && d.z < hi) {
                int p = atomicAdd(&deg[d.z], 1);
                if (p < CSR_STRIDE)
                    csr[d.z * CSR_STRIDE + p] = __builtin_nontemporal_load(ei + e0 + 2);
            }
            if (d.w >= lo && d.w < hi) {
                int p = atomicAdd(&deg[d.w], 1);
                if (p < CSR_STRIDE)
                    csr[d.w * CSR_STRIDE + p] = __builtin_nontemporal_load(ei + e0 + 3);
            }
        }
    }
}

// ---- fused GIN layer v5: paired-row gather (16 loads in flight per 16-lane
// group) + fp32 2-GEMM MLP. v5 pairing gained ~4us over v4 serial rows.
__global__ __launch_bounds__(512, 6) void gather_mlp_kernel(
    const uint2* __restrict__ hin, uint2* __restrict__ hout,
    const int* __restrict__ csr, const int* __restrict__ deg,
    const float* __restrict__ W1, const float* __restrict__ b1,
    const float* __restrict__ W2, const float* __restrict__ b2)
{
    __shared__ float as[BLK_N][68];   // [r][36..67] = staged eidx, then agg/z tile
    __shared__ float ws[64][68];      // W1, then W2
    __shared__ int   sdeg[BLK_N];
    const int tid = threadIdx.x;
    const int tx = tid & 15, ty = tid >> 4;   // ty = group id 0..31
    const int sub = tx;
    const int n0 = blockIdx.x * BLK_N;

    // stage W1 (latency hidden behind gather)
#pragma unroll
    for (int t = 0; t < 2; ++t) {
        const int idx = t * 512 + tid;
        const int m = idx >> 4, kv = idx & 15;
        *(float4*)&ws[m][kv * 4] = *(const float4*)(W1 + (size_t)m * N_HID + kv * 4);
    }
    // stage deg
    if (tid < BLK_N) {
        const int node = n0 + tid;
        sdeg[tid] = (node < N_NODES) ? deg[node] : 0;
    }
    // stage edge indices: first 32 slots per node -> as[r][36..67]
#pragma unroll
    for (int t = 0; t < 2; ++t) {
        const int idx = t * 512 + tid;        // 0..1023
        const int r = idx >> 3, s4 = idx & 7;
        const int node = n0 + r;
        int4 v = make_int4(0, 0, 0, 0);
        if (node < N_NODES)
            v = *(const int4*)(csr + (size_t)node * CSR_STRIDE + s4 * 4);
        *(int4*)((int*)&as[r][36] + s4 * 4) = v;
    }
    __syncthreads();

    // gather: group ty owns rows ty, ty+32, ty+64, ty+96; processed as pairs
    // (rA, rB=rA+32) with both rows' loads in flight simultaneously.
    for (int pp = 0; pp < 2; ++pp) {
        const int rA = ty + 64 * pp;
        const int rB = rA + 32;
        const int nodeA = n0 + rA;
        const int nodeB = n0 + rB;
        float aAx = 0.f, aAy = 0.f, aAz = 0.f, aAw = 0.f;
        float bAx = 0.f, bAy = 0.f, bAz = 0.f, bAw = 0.f;
        float aBx = 0.f, aBy = 0.f, aBz = 0.f, aBw = 0.f;
        float bBx = 0.f, bBy = 0.f, bBz = 0.f, bBw = 0.f;
        int nA = 0, nB = 0;
        if (nodeA < N_NODES) {
            nA = sdeg[rA]; nA = nA > CSR_STRIDE ? CSR_STRIDE : nA;
            const uint2 s = hin[(size_t)nodeA * 16 + sub];   // self term
            aAx = bflo(s.x); aAy = bfhi(s.x); aAz = bflo(s.y); aAw = bfhi(s.y);
        }
        if (nodeB < N_NODES) {
            nB = sdeg[rB]; nB = nB > CSR_STRIDE ? CSR_STRIDE : nB;
            const uint2 s = hin[(size_t)nodeB * 16 + sub];   // self term
            aBx = bflo(s.x); aBy = bfhi(s.x); aBz = bflo(s.y); aBw = bfhi(s.y);
        }
        const int nnA = nA > EMAX_LDS ? EMAX_LDS : nA;
        const int nnB = nB > EMAX_LDS ? EMAX_LDS : nB;
        const int* epA = (const int*)&as[rA][36];
        const int* epB = (const int*)&as[rB][36];
        const int mx = nnA > nnB ? nnA : nnB;
        for (int eb = 0; eb < mx; eb += 8) {
            uint2 rvA[8], rvB[8];
            const bool doA = eb < nnA;
            const bool doB = eb < nnB;
            if (doA) {
#pragma unroll
                for (int u = 0; u < 8; ++u) {
                    const int idx = eb + u;
                    const int cl = idx < nnA ? idx : nnA - 1;  // clamp: slots>=deg are poison
                    rvA[u] = hin[(size_t)epA[cl] * 16 + sub];
                }
            }
            if (doB) {
#pragma unroll
                for (int u = 0; u < 8; ++u) {
                    const int idx = eb + u;
                    const int cl = idx < nnB ? idx : nnB - 1;
                    rvB[u] = hin[(size_t)epB[cl] * 16 + sub];
                }
            }
            if (doA) {
#pragma unroll
                for (int u = 0; u < 8; u += 2) {
                    if (eb + u < nnA) {
                        aAx += bflo(rvA[u].x); aAy += bfhi(rvA[u].x);
                        aAz += bflo(rvA[u].y); aAw += bfhi(rvA[u].y);
                    }
                    if (eb + u + 1 < nnA) {
                        bAx += bflo(rvA[u + 1].x); bAy += bfhi(rvA[u + 1].x);
                        bAz += bflo(rvA[u + 1].y); bAw += bfhi(rvA[u + 1].y);
                    }
                }
            }
            if (doB) {
#pragma unroll
                for (int u = 0; u < 8; u += 2) {
                    if (eb + u < nnB) {
                        aBx += bflo(rvB[u].x); aBy += bfhi(rvB[u].x);
                        aBz += bflo(rvB[u].y); aBw += bfhi(rvB[u].y);
                    }
                    if (eb + u + 1 < nnB) {
                        bBx += bflo(rvB[u + 1].x); bBy += bfhi(rvB[u + 1].x);
                        bBz += bflo(rvB[u + 1].y); bBw += bfhi(rvB[u + 1].y);
                    }
                }
            }
        }
        for (int t = EMAX_LDS; t < nA; ++t) { // rare tail (P~1e-4)
            const int s0 = csr[(size_t)nodeA * CSR_STRIDE + t];
            const uint2 a = hin[(size_t)s0 * 16 + sub];
            aAx += bflo(a.x); aAy += bfhi(a.x);
            aAz += bflo(a.y); aAw += bfhi(a.y);
        }
        for (int t = EMAX_LDS; t < nB; ++t) {
            const int s0 = csr[(size_t)nodeB * CSR_STRIDE + t];
            const uint2 a = hin[(size_t)s0 * 16 + sub];
            aBx += bflo(a.x); aBy += bfhi(a.x);
            aBz += bflo(a.y); aBw += bfhi(a.y);
        }
        // write result rows (overlap these rows' eidx regions — reads done)
        *(float4*)&as[rA][sub * 4] =
            make_float4(aAx + bAx, aAy + bAy, aAz + bAz, aAw + bAw);
        *(float4*)&as[rB][sub * 4] =
            make_float4(aBx + bBx, aBy + bBy, aBz + bBz, aBw + bBw);
    }
    __syncthreads();

    // phase 1: z = relu(agg @ W1 + b1); rows ty + 32*i
    float acc[4][4];
#pragma unroll
    for (int i = 0; i < 4; ++i)
#pragma unroll
        for (int j = 0; j < 4; ++j) acc[i][j] = 0.f;
#pragma unroll 2
    for (int k4 = 0; k4 < 16; ++k4) {
        float4 a[4], bb[4];
#pragma unroll
        for (int i = 0; i < 4; ++i)
            a[i] = *(const float4*)&as[ty + 32 * i][k4 * 4];
#pragma unroll
        for (int j = 0; j < 4; ++j)
            bb[j] = *(const float4*)&ws[k4 * 4 + j][tx * 4];
#pragma unroll
        for (int i = 0; i < 4; ++i) {
            const float* ap = (const float*)&a[i];
#pragma unroll
            for (int j = 0; j < 4; ++j) {
                const float* bp = (const float*)&bb[j];
#pragma unroll
                for (int c = 0; c < 4; ++c)
                    acc[i][c] = fmaf(ap[j], bp[c], acc[i][c]);
            }
        }
    }
    const float4 bias1 = *(const float4*)(b1 + tx * 4);
    float4 z[4];
#pragma unroll
    for (int i = 0; i < 4; ++i) {
        z[i].x = fmaxf(acc[i][0] + bias1.x, 0.f);
        z[i].y = fmaxf(acc[i][1] + bias1.y, 0.f);
        z[i].z = fmaxf(acc[i][2] + bias1.z, 0.f);
        z[i].w = fmaxf(acc[i][3] + bias1.w, 0.f);
    }
    __syncthreads();               // all phase-1 reads of as/ws done
#pragma unroll
    for (int i = 0; i < 4; ++i)
        *(float4*)&as[ty + 32 * i][tx * 4] = z[i];
#pragma unroll
    for (int t = 0; t < 2; ++t) {
        const int idx = t * 512 + tid;
        const int m = idx >> 4, kv = idx & 15;
        *(float4*)&ws[m][kv * 4] = *(const float4*)(W2 + (size_t)m * N_HID + kv * 4);
    }
    __syncthreads();

    // phase 2: h = relu(z @ W2 + b2), bf16 out
#pragma unroll
    for (int i = 0; i < 4; ++i)
#pragma unroll
        for (int j = 0; j < 4; ++j) acc[i][j] = 0.f;
#pragma unroll 2
    for (int k4 = 0; k4 < 16; ++k4) {
        float4 a[4], bb[4];
#pragma unroll
        for (int i = 0; i < 4; ++i)
            a[i] = *(const float4*)&as[ty + 32 * i][k4 * 4];
#pragma unroll
        for (int j = 0; j < 4; ++j)
            bb[j] = *(const float4*)&ws[k4 * 4 + j][tx * 4];
#pragma unroll
        for (int i = 0; i < 4; ++i) {
            const float* ap = (const float*)&a[i];
#pragma unroll
            for (int j = 0; j < 4; ++j) {
                const float* bp = (const float*)&bb[j];
#pragma unroll
                for (int c = 0; c < 4; ++c)
                    acc[i][c] = fmaf(ap[j], bp[c], acc[i][c]);
            }
        }
    }
    const float4 bias2 = *(const float4*)(b2 + tx * 4);
#pragma unroll
    for (int i = 0; i < 4; ++i) {
        const int node = n0 + ty + 32 * i;
        if (node < N_NODES) {
            hout[(size_t)node * 16 + tx] = make_uint2(
                pack2(fmaxf(acc[i][0] + bias2.x, 0.f),
                      fmaxf(acc[i][1] + bias2.y, 0.f)),
                pack2(fmaxf(acc[i][2] + bias2.z, 0.f),
                      fmaxf(acc[i][3] + bias2.w, 0.f)));
        }
    }
}

// ---- fused pool+head: block per graph; wave 0 finishes post/ro/log_softmax
// in-register from the pooled row. h is bf16. ----
__global__ __launch_bounds__(256) void pool_head_kernel(
    const unsigned short* __restrict__ h, const int* __restrict__ batch,
    const float* __restrict__ Wp, const float* __restrict__ bp,
    const float* __restrict__ Wr, const float* __restrict__ br,
    float* __restrict__ out)
{
    const int graph = blockIdx.x;
    int l = 0, r = N_NODES;
    while (l < r) { int m = (l + r) >> 1; if (batch[m] < graph) l = m + 1; else r = m; }
    const int lo = l;
    r = N_NODES;
    while (l < r) { int m = (l + r) >> 1; if (batch[m] < graph + 1) l = m + 1; else r = m; }
    const int hi = l;

    const int lane = threadIdx.x & 63;
    const int wave = threadIdx.x >> 6;
    float acc = 0.0f;
    for (int i = lo + wave; i < hi; i += 4)
        acc += __uint_as_float(((unsigned)h[(size_t)i * N_HID + lane]) << 16);
    __shared__ float sacc[4][N_HID];
    sacc[wave][lane] = acc;
    __syncthreads();
    if (wave != 0) return;

    const float gv = sacc[0][lane] + sacc[1][lane] + sacc[2][lane] + sacc[3][lane];
    float acc2 = bp[lane];
#pragma unroll
    for (int k = 0; k < N_HID; ++k) {
        const float gk = __int_as_float(
            __builtin_amdgcn_readlane(__float_as_int(gv), k));  // exec-ignoring
        acc2 = fmaf(gk, Wp[k * N_HID + lane], acc2);
    }
    const float y = fmaxf(acc2, 0.f);

    float logit = (lane < N_CLASS) ? br[lane] : 0.f;
#pragma unroll
    for (int k = 0; k < N_HID; ++k) {
        const float yk = __int_as_float(
            __builtin_amdgcn_readlane(__float_as_int(y), k));
        if (lane < N_CLASS)
            logit = fmaf(yk, Wr[k * N_CLASS + lane], logit);
    }

    __shared__ float slog[N_CLASS];
    if (lane < N_CLASS) slog[lane] = logit;
    if (lane < N_CLASS) {
        float m = -INFINITY;
#pragma unroll
        for (int c = 0; c < N_CLASS; ++c) m = fmaxf(m, slog[c]);
        float sum = 0.0f;
#pragma unroll
        for (int c = 0; c < N_CLASS; ++c) sum += expf(slog[c] - m);
        out[(size_t)graph * N_CLASS + lane] = logit - m - logf(sum);
    }
}

extern "C" void kernel_launch(void* const* d_in, const int* in_sizes, int n_in,
                              void* d_out, int out_size, void* d_ws, size_t ws_size,
                              hipStream_t stream)
{
    const float* x       = (const float*)d_in[0];
    const int*   ei      = (const int*)d_in[1];   // [2, E]: row0=src, row1=dst
    const int*   batch   = (const int*)d_in[2];
    const float* pre_w   = (const float*)d_in[3];
    const float* pre_b   = (const float*)d_in[4];
    const float* conv_w1 = (const float*)d_in[5];
    const float* conv_b1 = (const float*)d_in[6];
    const float* conv_w2 = (const float*)d_in[7];
    const float* conv_b2 = (const float*)d_in[8];
    const float* post_w  = (const float*)d_in[9];
    const float* post_b  = (const float*)d_in[10];
    const float* ro_w    = (const float*)d_in[11];
    const float* ro_b    = (const float*)d_in[12];
    float* out = (float*)d_out;

    // workspace layout (~51.6 MB)
    uint2* h0   = (uint2*)d_ws;                       // 12.8 MB (bf16 h)
    uint2* h1   = h0 + (size_t)N_NODES * 16;          // 12.8 MB
    int*   deg  = (int*)(h1 + (size_t)N_NODES * 16);  // 400 KB
    int*   csr  = deg + N_NODES;                      // 25.6 MB fixed-stride

    (void)hipMemsetAsync(deg, 0, N_NODES * sizeof(int), stream);

    // fused pre + hist: independent producer kernels co-resident on the CUs
    pre_hist_kernel<<<FUSED_BLOCKS, 256, 0, stream>>>(
        x, pre_w, pre_b, h0, ei, deg, csr);

    // 3 fused GIN layers, h ping-pong h0 -> h1 -> h0 -> h1
    gather_mlp_kernel<<<NT2, 512, 0, stream>>>(
        h0, h1, csr, deg,
        conv_w1, conv_b1, conv_w2, conv_b2);
    gather_mlp_kernel<<<NT2, 512, 0, stream>>>(
        h1, h0, csr, deg,
        conv_w1 + N_HID * N_HID, conv_b1 + N_HID,
        conv_w2 + N_HID * N_HID, conv_b2 + N_HID);
    gather_mlp_kernel<<<NT2, 512, 0, stream>>>(
        h0, h1, csr, deg,
        conv_w1 + 2 * N_HID * N_HID, conv_b1 + 2 * N_HID,
        conv_w2 + 2 * N_HID * N_HID, conv_b2 + 2 * N_HID);

    pool_head_kernel<<<N_GRAPHS, 256, 0, stream>>>(
        (const unsigned short*)h1, batch, post_w, post_b, ro_w, ro_b, out);
}

// Round 8
// 419.534 us; speedup vs baseline: 1.0610x; 1.0610x over previous
//
#include <hip/hip_runtime.h>
#include <math.h>

#define N_NODES  100000
#define N_FEAT   128
#define N_HID    64
#define N_CLASS  10
#define N_GRAPHS 1000
#define N_EDGES  1600000
#define NTILES   1563      // ceil(100000/64)  (pre tiles; gather blocks)
#define BLK_N    128       // mlp tile
#define NT2      782       // ceil(100000/128)
#define HF_GROUPS 8        // concurrent dst ranges
#define HF_RANGE 12500     // 100000/8; csr window 3.2 MB
#define HF_BLOCKS 2048
#define CSR_STRIDE 64      // fixed bucket per node; P(deg>=64)~1e-20 @ Poisson(16)
#define EMAX_LDS 32        // staged slots per node; P(deg>32)~1e-4 -> global tail

typedef int iv4 __attribute__((ext_vector_type(4)));  // for nontemporal builtin

// ---- bf16 helpers: h stored bf16 (row = 128 B); all arithmetic fp32.
__device__ __forceinline__ float bflo(unsigned u) { return __uint_as_float(u << 16); }
__device__ __forceinline__ float bfhi(unsigned u) { return __uint_as_float(u & 0xffff0000u); }
__device__ __forceinline__ unsigned bf_rne(float f) {
    unsigned u = __float_as_uint(f);
    return (u + 0x7fffu + ((u >> 16) & 1u)) >> 16;
}
__device__ __forceinline__ unsigned pack2(float a, float b) {
    return bf_rne(a) | (bf_rne(b) << 16);
}

// ---- pre: h0 = x @ pre_w + pre_b (bf16 out). 64-node tile. (v6 lesson:
// do NOT fuse with hist -- pre's LDS/VGPR starves hist's residency, 155us
// fused vs ~107 serial.)
__global__ __launch_bounds__(256, 4) void pre_kernel(
    const float* __restrict__ x, const float* __restrict__ W,
    const float* __restrict__ b, uint2* __restrict__ h)
{
    __shared__ float xs[64][68];
    __shared__ float ws[64][68];
    const int tid = threadIdx.x;
    const int tx = tid & 15, ty = tid >> 4;
    const int n0 = blockIdx.x * 64;

    float acc[4][4];
#pragma unroll
    for (int i = 0; i < 4; ++i)
#pragma unroll
        for (int j = 0; j < 4; ++j) acc[i][j] = 0.f;

    for (int p = 0; p < 2; ++p) {
        __syncthreads();
#pragma unroll
        for (int t = 0; t < 4; ++t) {
            const int idx = t * 256 + tid;
            const int m = idx >> 4, kv = idx & 15;
            float4 v = make_float4(0.f, 0.f, 0.f, 0.f);
            if (n0 + m < N_NODES)
                v = *(const float4*)(x + (size_t)(n0 + m) * N_FEAT + p * 64 + kv * 4);
            *(float4*)&xs[m][kv * 4] = v;
            *(float4*)&ws[m][kv * 4] =
                *(const float4*)(W + (size_t)(p * 64 + m) * N_HID + kv * 4);
        }
        __syncthreads();
#pragma unroll 2
        for (int k4 = 0; k4 < 16; ++k4) {
            float4 a[4], bb[4];
#pragma unroll
            for (int i = 0; i < 4; ++i)
                a[i] = *(const float4*)&xs[ty + 16 * i][k4 * 4];
#pragma unroll
            for (int j = 0; j < 4; ++j)
                bb[j] = *(const float4*)&ws[k4 * 4 + j][tx * 4];
#pragma unroll
            for (int i = 0; i < 4; ++i) {
                const float* ap = (const float*)&a[i];
#pragma unroll
                for (int j = 0; j < 4; ++j) {
                    const float* bp = (const float*)&bb[j];
#pragma unroll
                    for (int c = 0; c < 4; ++c)
                        acc[i][c] = fmaf(ap[j], bp[c], acc[i][c]);
                }
            }
        }
    }

    const float4 bias = *(const float4*)(b + tx * 4);
#pragma unroll
    for (int i = 0; i < 4; ++i) {
        const int node = n0 + ty + 16 * i;
        if (node < N_NODES) {
            h[(size_t)node * 16 + tx] = make_uint2(
                pack2(acc[i][0] + bias.x, acc[i][1] + bias.y),
                pack2(acc[i][2] + bias.z, acc[i][3] + bias.w));
        }
    }
}

// ---- hist+fill v3 (best measured 76.5us): 8 concurrent dst-ranges with
// XCD affinity, NT dst+src reads. v4 lesson (705us): never concentrate the
// 1.6M returning atomics onto few cache lines. v0-v3 all 77-86us regardless
// of write pattern (92/79/66 MB) -> near the mixed scattered-write/atomic
// effective-BW floor (~1.8 TB/s), not further improvable by hinting.
__global__ __launch_bounds__(256) void hist_fill_kernel(
    const int* __restrict__ ei, int* __restrict__ deg, int* __restrict__ csr)
{
    const int r   = blockIdx.x & (HF_GROUPS - 1);
    const int g   = blockIdx.x >> 3;
    const int lo  = r * HF_RANGE;
    const int hi  = lo + HF_RANGE;
    const int gsz = (gridDim.x >> 3) * blockDim.x;
    const int t0  = g * blockDim.x + threadIdx.x;
    const iv4* dst4 = (const iv4*)(ei + N_EDGES);
    for (int q = t0; q < N_EDGES / 4; q += gsz) {
        const iv4 d = __builtin_nontemporal_load(dst4 + q);
        const int e0 = q * 4;
        if (d.x >= lo && d.x < hi) {
            int p = atomicAdd(&deg[d.x], 1);
            if (p < CSR_STRIDE)
                csr[d.x * CSR_STRIDE + p] = __builtin_nontemporal_load(ei + e0);
        }
        if (d.y >= lo && d.y < hi) {
            int p = atomicAdd(&deg[d.y], 1);
            if (p < CSR_STRIDE)
                csr[d.y * CSR_STRIDE + p] = __builtin_nontemporal_load(ei + e0 + 1);
        }
        if (d.z >= lo && d.z < hi) {
            int p = atomicAdd(&deg[d.z], 1);
            if (p < CSR_STRIDE)
                csr[d.z * CSR_STRIDE + p] = __builtin_nontemporal_load(ei + e0 + 2);
        }
        if (d.w >= lo && d.w < hi) {
            int p = atomicAdd(&deg[d.w], 1);
            if (p < CSR_STRIDE)
                csr[d.w * CSR_STRIDE + p] = __builtin_nontemporal_load(ei + e0 + 3);
        }
    }
}

// ---- gather v7 (split from MLP): 256 threads, 64 nodes/block, LDS only
// 8.7 KB -> ~2x the resident waves of the fused 52.7KB kernel -> ~2x loads
// in flight per CU (the gather is random-L3-read latency-bound: 205 MB/layer
// at ~2.7 TB/s effective in the fused kernel). Paired rows keep 16 loads in
// flight per 16-lane group (v5, +4us). agg written bf16 IN-PLACE into the
// layer's output h buffer (mlp_kernel stages a block's rows to LDS + syncs
// before overwriting exactly those rows; blocks disjoint -> no race, no
// extra workspace).
__global__ __launch_bounds__(256, 6) void gather_kernel(
    const uint2* __restrict__ hin, uint2* __restrict__ aggb,
    const int* __restrict__ csr, const int* __restrict__ deg)
{
    __shared__ int es[64][32];
    __shared__ int sdeg[64];
    const int tid = threadIdx.x;
    const int tx = tid & 15, ty = tid >> 4;   // 16 groups of 16 lanes
    const int sub = tx;
    const int n0 = blockIdx.x * 64;

    if (tid < 64) {
        const int node = n0 + tid;
        sdeg[tid] = (node < N_NODES) ? deg[node] : 0;
    }
#pragma unroll
    for (int t = 0; t < 2; ++t) {
        const int idx = t * 256 + tid;        // 0..511 int4 slots
        const int r = idx >> 3, s4 = idx & 7;
        const int node = n0 + r;
        int4 v = make_int4(0, 0, 0, 0);
        if (node < N_NODES)
            v = *(const int4*)(csr + (size_t)node * CSR_STRIDE + s4 * 4);
        *(int4*)&es[r][s4 * 4] = v;
    }
    __syncthreads();

    // group ty owns rows ty, ty+16, ty+32, ty+48; pairs (rA, rB=rA+16)
    for (int pp = 0; pp < 2; ++pp) {
        const int rA = ty + 32 * pp;
        const int rB = rA + 16;
        const int nodeA = n0 + rA;
        const int nodeB = n0 + rB;
        float aAx = 0.f, aAy = 0.f, aAz = 0.f, aAw = 0.f;
        float bAx = 0.f, bAy = 0.f, bAz = 0.f, bAw = 0.f;
        float aBx = 0.f, aBy = 0.f, aBz = 0.f, aBw = 0.f;
        float bBx = 0.f, bBy = 0.f, bBz = 0.f, bBw = 0.f;
        int nA = 0, nB = 0;
        if (nodeA < N_NODES) {
            nA = sdeg[rA]; nA = nA > CSR_STRIDE ? CSR_STRIDE : nA;
            const uint2 s = hin[(size_t)nodeA * 16 + sub];   // self term
            aAx = bflo(s.x); aAy = bfhi(s.x); aAz = bflo(s.y); aAw = bfhi(s.y);
        }
        if (nodeB < N_NODES) {
            nB = sdeg[rB]; nB = nB > CSR_STRIDE ? CSR_STRIDE : nB;
            const uint2 s = hin[(size_t)nodeB * 16 + sub];   // self term
            aBx = bflo(s.x); aBy = bfhi(s.x); aBz = bflo(s.y); aBw = bfhi(s.y);
        }
        const int nnA = nA > EMAX_LDS ? EMAX_LDS : nA;
        const int nnB = nB > EMAX_LDS ? EMAX_LDS : nB;
        const int* epA = &es[rA][0];
        const int* epB = &es[rB][0];
        const int mx = nnA > nnB ? nnA : nnB;
        for (int eb = 0; eb < mx; eb += 8) {
            uint2 rvA[8], rvB[8];
            const bool doA = eb < nnA;
            const bool doB = eb < nnB;
            if (doA) {
#pragma unroll
                for (int u = 0; u < 8; ++u) {
                    const int idx = eb + u;
                    const int cl = idx < nnA ? idx : nnA - 1;  // clamp: slots>=deg are poison
                    rvA[u] = hin[(size_t)epA[cl] * 16 + sub];
                }
            }
            if (doB) {
#pragma unroll
                for (int u = 0; u < 8; ++u) {
                    const int idx = eb + u;
                    const int cl = idx < nnB ? idx : nnB - 1;
                    rvB[u] = hin[(size_t)epB[cl] * 16 + sub];
                }
            }
            if (doA) {
#pragma unroll
                for (int u = 0; u < 8; u += 2) {
                    if (eb + u < nnA) {
                        aAx += bflo(rvA[u].x); aAy += bfhi(rvA[u].x);
                        aAz += bflo(rvA[u].y); aAw += bfhi(rvA[u].y);
                    }
                    if (eb + u + 1 < nnA) {
                        bAx += bflo(rvA[u + 1].x); bAy += bfhi(rvA[u + 1].x);
                        bAz += bflo(rvA[u + 1].y); bAw += bfhi(rvA[u + 1].y);
                    }
                }
            }
            if (doB) {
#pragma unroll
                for (int u = 0; u < 8; u += 2) {
                    if (eb + u < nnB) {
                        aBx += bflo(rvB[u].x); aBy += bfhi(rvB[u].x);
                        aBz += bflo(rvB[u].y); aBw += bfhi(rvB[u].y);
                    }
                    if (eb + u + 1 < nnB) {
                        bBx += bflo(rvB[u + 1].x); bBy += bfhi(rvB[u + 1].x);
                        bBz += bflo(rvB[u + 1].y); bBw += bfhi(rvB[u + 1].y);
                    }
                }
            }
        }
        for (int t = EMAX_LDS; t < nA; ++t) { // rare tail (P~1e-4)
            const int s0 = csr[(size_t)nodeA * CSR_STRIDE + t];
            const uint2 a = hin[(size_t)s0 * 16 + sub];
            aAx += bflo(a.x); aAy += bfhi(a.x);
            aAz += bflo(a.y); aAw += bfhi(a.y);
        }
        for (int t = EMAX_LDS; t < nB; ++t) {
            const int s0 = csr[(size_t)nodeB * CSR_STRIDE + t];
            const uint2 a = hin[(size_t)s0 * 16 + sub];
            aBx += bflo(a.x); aBy += bfhi(a.x);
            aBz += bflo(a.y); aBw += bfhi(a.y);
        }
        if (nodeA < N_NODES)
            aggb[(size_t)nodeA * 16 + sub] = make_uint2(
                pack2(aAx + bAx, aAy + bAy), pack2(aAz + bAz, aAw + bAw));
        if (nodeB < N_NODES)
            aggb[(size_t)nodeB * 16 + sub] = make_uint2(
                pack2(aBx + bBx, aBy + bBy), pack2(aBz + bBz, aBw + bBw));
    }
}

// ---- mlp v7: in-place h = relu(relu(agg@W1+b1)@W2+b2) on a 128-row tile.
// Stages agg rows (bf16) to LDS fp32, syncs, then the two GEMMs overwrite
// the same rows -- per-block in-place is race-free.
__global__ __launch_bounds__(512, 6) void mlp_kernel(
    uint2* __restrict__ hbuf,
    const float* __restrict__ W1, const float* __restrict__ b1,
    const float* __restrict__ W2, const float* __restrict__ b2)
{
    __shared__ float as[BLK_N][68];
    __shared__ float ws[64][68];
    const int tid = threadIdx.x;
    const int tx = tid & 15, ty = tid >> 4;   // ty 0..31
    const int n0 = blockIdx.x * BLK_N;

    // stage W1
#pragma unroll
    for (int t = 0; t < 2; ++t) {
        const int idx = t * 512 + tid;
        const int m = idx >> 4, kv = idx & 15;
        *(float4*)&ws[m][kv * 4] = *(const float4*)(W1 + (size_t)m * N_HID + kv * 4);
    }
    // stage agg rows -> fp32 LDS
#pragma unroll
    for (int t = 0; t < 4; ++t) {
        const int idx = t * 512 + tid;        // 0..2047
        const int m = idx >> 4, kv = idx & 15;
        uint2 v = make_uint2(0, 0);
        if (n0 + m < N_NODES) v = hbuf[(size_t)(n0 + m) * 16 + kv];
        as[m][kv * 4 + 0] = bflo(v.x); as[m][kv * 4 + 1] = bfhi(v.x);
        as[m][kv * 4 + 2] = bflo(v.y); as[m][kv * 4 + 3] = bfhi(v.y);
    }
    __syncthreads();

    // phase 1: z = relu(agg @ W1 + b1); rows ty + 32*i
    float acc[4][4];
#pragma unroll
    for (int i = 0; i < 4; ++i)
#pragma unroll
        for (int j = 0; j < 4; ++j) acc[i][j] = 0.f;
#pragma unroll 2
    for (int k4 = 0; k4 < 16; ++k4) {
        float4 a[4], bb[4];
#pragma unroll
        for (int i = 0; i < 4; ++i)
            a[i] = *(const float4*)&as[ty + 32 * i][k4 * 4];
#pragma unroll
        for (int j = 0; j < 4; ++j)
            bb[j] = *(const float4*)&ws[k4 * 4 + j][tx * 4];
#pragma unroll
        for (int i = 0; i < 4; ++i) {
            const float* ap = (const float*)&a[i];
#pragma unroll
            for (int j = 0; j < 4; ++j) {
                const float* bp = (const float*)&bb[j];
#pragma unroll
                for (int c = 0; c < 4; ++c)
                    acc[i][c] = fmaf(ap[j], bp[c], acc[i][c]);
            }
        }
    }
    const float4 bias1 = *(const float4*)(b1 + tx * 4);
    float4 z[4];
#pragma unroll
    for (int i = 0; i < 4; ++i) {
        z[i].x = fmaxf(acc[i][0] + bias1.x, 0.f);
        z[i].y = fmaxf(acc[i][1] + bias1.y, 0.f);
        z[i].z = fmaxf(acc[i][2] + bias1.z, 0.f);
        z[i].w = fmaxf(acc[i][3] + bias1.w, 0.f);
    }
    __syncthreads();
#pragma unroll
    for (int i = 0; i < 4; ++i)
        *(float4*)&as[ty + 32 * i][tx * 4] = z[i];
#pragma unroll
    for (int t = 0; t < 2; ++t) {
        const int idx = t * 512 + tid;
        const int m = idx >> 4, kv = idx & 15;
        *(float4*)&ws[m][kv * 4] = *(const float4*)(W2 + (size_t)m * N_HID + kv * 4);
    }
    __syncthreads();

    // phase 2: h = relu(z @ W2 + b2), bf16 out (in-place)
#pragma unroll
    for (int i = 0; i < 4; ++i)
#pragma unroll
        for (int j = 0; j < 4; ++j) acc[i][j] = 0.f;
#pragma unroll 2
    for (int k4 = 0; k4 < 16; ++k4) {
        float4 a[4], bb[4];
#pragma unroll
        for (int i = 0; i < 4; ++i)
            a[i] = *(const float4*)&as[ty + 32 * i][k4 * 4];
#pragma unroll
        for (int j = 0; j < 4; ++j)
            bb[j] = *(const float4*)&ws[k4 * 4 + j][tx * 4];
#pragma unroll
        for (int i = 0; i < 4; ++i) {
            const float* ap = (const float*)&a[i];
#pragma unroll
            for (int j = 0; j < 4; ++j) {
                const float* bp = (const float*)&bb[j];
#pragma unroll
                for (int c = 0; c < 4; ++c)
                    acc[i][c] = fmaf(ap[j], bp[c], acc[i][c]);
            }
        }
    }
    const float4 bias2 = *(const float4*)(b2 + tx * 4);
#pragma unroll
    for (int i = 0; i < 4; ++i) {
        const int node = n0 + ty + 32 * i;
        if (node < N_NODES) {
            hbuf[(size_t)node * 16 + tx] = make_uint2(
                pack2(fmaxf(acc[i][0] + bias2.x, 0.f),
                      fmaxf(acc[i][1] + bias2.y, 0.f)),
                pack2(fmaxf(acc[i][2] + bias2.z, 0.f),
                      fmaxf(acc[i][3] + bias2.w, 0.f)));
        }
    }
}

// ---- fused pool+head: block per graph; wave 0 finishes post/ro/log_softmax
// in-register from the pooled row. h is bf16. ----
__global__ __launch_bounds__(256) void pool_head_kernel(
    const unsigned short* __restrict__ h, const int* __restrict__ batch,
    const float* __restrict__ Wp, const float* __restrict__ bp,
    const float* __restrict__ Wr, const float* __restrict__ br,
    float* __restrict__ out)
{
    const int graph = blockIdx.x;
    int l = 0, r = N_NODES;
    while (l < r) { int m = (l + r) >> 1; if (batch[m] < graph) l = m + 1; else r = m; }
    const int lo = l;
    r = N_NODES;
    while (l < r) { int m = (l + r) >> 1; if (batch[m] < graph + 1) l = m + 1; else r = m; }
    const int hi = l;

    const int lane = threadIdx.x & 63;
    const int wave = threadIdx.x >> 6;
    float acc = 0.0f;
    for (int i = lo + wave; i < hi; i += 4)
        acc += __uint_as_float(((unsigned)h[(size_t)i * N_HID + lane]) << 16);
    __shared__ float sacc[4][N_HID];
    sacc[wave][lane] = acc;
    __syncthreads();
    if (wave != 0) return;

    const float gv = sacc[0][lane] + sacc[1][lane] + sacc[2][lane] + sacc[3][lane];
    float acc2 = bp[lane];
#pragma unroll
    for (int k = 0; k < N_HID; ++k) {
        const float gk = __int_as_float(
            __builtin_amdgcn_readlane(__float_as_int(gv), k));
        acc2 = fmaf(gk, Wp[k * N_HID + lane], acc2);
    }
    const float y = fmaxf(acc2, 0.f);

    float logit = (lane < N_CLASS) ? br[lane] : 0.f;
#pragma unroll
    for (int k = 0; k < N_HID; ++k) {
        const float yk = __int_as_float(
            __builtin_amdgcn_readlane(__float_as_int(y), k));
        if (lane < N_CLASS)
            logit = fmaf(yk, Wr[k * N_CLASS + lane], logit);
    }

    __shared__ float slog[N_CLASS];
    if (lane < N_CLASS) slog[lane] = logit;
    if (lane < N_CLASS) {
        float m = -INFINITY;
#pragma unroll
        for (int c = 0; c < N_CLASS; ++c) m = fmaxf(m, slog[c]);
        float sum = 0.0f;
#pragma unroll
        for (int c = 0; c < N_CLASS; ++c) sum += expf(slog[c] - m);
        out[(size_t)graph * N_CLASS + lane] = logit - m - logf(sum);
    }
}

extern "C" void kernel_launch(void* const* d_in, const int* in_sizes, int n_in,
                              void* d_out, int out_size, void* d_ws, size_t ws_size,
                              hipStream_t stream)
{
    const float* x       = (const float*)d_in[0];
    const int*   ei      = (const int*)d_in[1];   // [2, E]: row0=src, row1=dst
    const int*   batch   = (const int*)d_in[2];
    const float* pre_w   = (const float*)d_in[3];
    const float* pre_b   = (const float*)d_in[4];
    const float* conv_w1 = (const float*)d_in[5];
    const float* conv_b1 = (const float*)d_in[6];
    const float* conv_w2 = (const float*)d_in[7];
    const float* conv_b2 = (const float*)d_in[8];
    const float* post_w  = (const float*)d_in[9];
    const float* post_b  = (const float*)d_in[10];
    const float* ro_w    = (const float*)d_in[11];
    const float* ro_b    = (const float*)d_in[12];
    float* out = (float*)d_out;

    // workspace layout (~51.6 MB)
    uint2* h0   = (uint2*)d_ws;                       // 12.8 MB (bf16 h)
    uint2* h1   = h0 + (size_t)N_NODES * 16;          // 12.8 MB
    int*   deg  = (int*)(h1 + (size_t)N_NODES * 16);  // 400 KB
    int*   csr  = deg + N_NODES;                      // 25.6 MB fixed-stride

    (void)hipMemsetAsync(deg, 0, N_NODES * sizeof(int), stream);

    pre_kernel<<<NTILES, 256, 0, stream>>>(x, pre_w, pre_b, h0);
    hist_fill_kernel<<<HF_BLOCKS, 256, 0, stream>>>(ei, deg, csr);

    // 3 GIN layers: gather (agg -> hout, bf16) then in-place MLP on hout
    gather_kernel<<<NTILES, 256, 0, stream>>>(h0, h1, csr, deg);
    mlp_kernel<<<NT2, 512, 0, stream>>>(h1, conv_w1, conv_b1, conv_w2, conv_b2);

    gather_kernel<<<NTILES, 256, 0, stream>>>(h1, h0, csr, deg);
    mlp_kernel<<<NT2, 512, 0, stream>>>(h0,
        conv_w1 + N_HID * N_HID, conv_b1 + N_HID,
        conv_w2 + N_HID * N_HID, conv_b2 + N_HID);

    gather_kernel<<<NTILES, 256, 0, stream>>>(h0, h1, csr, deg);
    mlp_kernel<<<NT2, 512, 0, stream>>>(h1,
        conv_w1 + 2 * N_HID * N_HID, conv_b1 + 2 * N_HID,
        conv_w2 + 2 * N_HID * N_HID, conv_b2 + 2 * N_HID);

    pool_head_kernel<<<N_GRAPHS, 256, 0, stream>>>(
        (const unsigned short*)h1, batch, post_w, post_b, ro_w, ro_b, out);
}

// Round 9
// 379.056 us; speedup vs baseline: 1.1743x; 1.1068x over previous
//
#include <hip/hip_runtime.h>
#include <math.h>

#define N_NODES  100000
#define N_FEAT   128
#define N_HID    64
#define N_CLASS  10
#define N_GRAPHS 1000
#define N_EDGES  1600000
#define NTILES   1563      // ceil(100000/64)   (pre kernel, 64-node tiles)
#define BLK_N    128       // gather_mlp tile
#define NT2      782       // ceil(100000/128)
#define HF_GROUPS 8        // concurrent dst ranges
#define HF_RANGE 12500     // 100000/8
#define HF_BLOCKS 2048
#define CSR_STRIDE 64      // fixed bucket per node; P(deg>=64)~1e-20 @ Poisson(16)
#define EMAX_LDS 32        // staged slots per node; P(deg>32)~1e-4 -> global tail
#define APITCH 72          // bf16 row pitch = 144 B (multiple of 16 B; 2-way banks)

typedef int iv4 __attribute__((ext_vector_type(4)));
typedef __attribute__((ext_vector_type(8))) __bf16 bf16x8;
typedef __attribute__((ext_vector_type(4))) float f32x4;

// ---- bf16 helpers: h stored bf16 (row = 128 B); arithmetic fp32 (MFMA fp32-accum).
__device__ __forceinline__ float bflo(unsigned u) { return __uint_as_float(u << 16); }
__device__ __forceinline__ float bfhi(unsigned u) { return __uint_as_float(u & 0xffff0000u); }
__device__ __forceinline__ unsigned bf_rne(float f) {
    unsigned u = __float_as_uint(f);
    return (u + 0x7fffu + ((u >> 16) & 1u)) >> 16;
}
__device__ __forceinline__ unsigned pack2(float a, float b) {
    return bf_rne(a) | (bf_rne(b) << 16);
}

// ---- pre: h0 = x @ pre_w + pre_b (bf16 out). (v6 lesson: never fuse with
// hist -- pre's LDS/VGPR starves hist residency, 155us fused vs ~107 serial.)
__global__ __launch_bounds__(256, 4) void pre_kernel(
    const float* __restrict__ x, const float* __restrict__ W,
    const float* __restrict__ b, uint2* __restrict__ h)
{
    __shared__ float xs[64][68];
    __shared__ float ws[64][68];
    const int tid = threadIdx.x;
    const int tx = tid & 15, ty = tid >> 4;
    const int n0 = blockIdx.x * 64;

    float acc[4][4];
#pragma unroll
    for (int i = 0; i < 4; ++i)
#pragma unroll
        for (int j = 0; j < 4; ++j) acc[i][j] = 0.f;

    for (int p = 0; p < 2; ++p) {
        __syncthreads();
#pragma unroll
        for (int t = 0; t < 4; ++t) {
            const int idx = t * 256 + tid;
            const int m = idx >> 4, kv = idx & 15;
            float4 v = make_float4(0.f, 0.f, 0.f, 0.f);
            if (n0 + m < N_NODES)
                v = *(const float4*)(x + (size_t)(n0 + m) * N_FEAT + p * 64 + kv * 4);
            *(float4*)&xs[m][kv * 4] = v;
            *(float4*)&ws[m][kv * 4] =
                *(const float4*)(W + (size_t)(p * 64 + m) * N_HID + kv * 4);
        }
        __syncthreads();
#pragma unroll 2
        for (int k4 = 0; k4 < 16; ++k4) {
            float4 a[4], bb[4];
#pragma unroll
            for (int i = 0; i < 4; ++i)
                a[i] = *(const float4*)&xs[ty + 16 * i][k4 * 4];
#pragma unroll
            for (int j = 0; j < 4; ++j)
                bb[j] = *(const float4*)&ws[k4 * 4 + j][tx * 4];
#pragma unroll
            for (int i = 0; i < 4; ++i) {
                const float* ap = (const float*)&a[i];
#pragma unroll
                for (int j = 0; j < 4; ++j) {
                    const float* bp = (const float*)&bb[j];
#pragma unroll
                    for (int c = 0; c < 4; ++c)
                        acc[i][c] = fmaf(ap[j], bp[c], acc[i][c]);
                }
            }
        }
    }

    const float4 bias = *(const float4*)(b + tx * 4);
#pragma unroll
    for (int i = 0; i < 4; ++i) {
        const int node = n0 + ty + 16 * i;
        if (node < N_NODES) {
            h[(size_t)node * 16 + tx] = make_uint2(
                pack2(acc[i][0] + bias.x, acc[i][1] + bias.y),
                pack2(acc[i][2] + bias.z, acc[i][3] + bias.w));
        }
    }
}

// ---- hist+fill v3 (best measured 76.5us): 8 concurrent dst-ranges, NT
// dst+src reads. v4 lesson (705us): never concentrate the 1.6M returning
// atomics onto few cache lines. v0-v3 all 77-86us regardless of write
// pattern -> effective-BW/atomic floor (~1.8 TB/s mixed), leave it.
__global__ __launch_bounds__(256) void hist_fill_kernel(
    const int* __restrict__ ei, int* __restrict__ deg, int* __restrict__ csr)
{
    const int r   = blockIdx.x & (HF_GROUPS - 1);
    const int g   = blockIdx.x >> 3;
    const int lo  = r * HF_RANGE;
    const int hi  = lo + HF_RANGE;
    const int gsz = (gridDim.x >> 3) * blockDim.x;
    const int t0  = g * blockDim.x + threadIdx.x;
    const iv4* dst4 = (const iv4*)(ei + N_EDGES);
    for (int q = t0; q < N_EDGES / 4; q += gsz) {
        const iv4 d = __builtin_nontemporal_load(dst4 + q);
        const int e0 = q * 4;
        if (d.x >= lo && d.x < hi) {
            int p = atomicAdd(&deg[d.x], 1);
            if (p < CSR_STRIDE)
                csr[d.x * CSR_STRIDE + p] = __builtin_nontemporal_load(ei + e0);
        }
        if (d.y >= lo && d.y < hi) {
            int p = atomicAdd(&deg[d.y], 1);
            if (p < CSR_STRIDE)
                csr[d.y * CSR_STRIDE + p] = __builtin_nontemporal_load(ei + e0 + 1);
        }
        if (d.z >= lo && d.z < hi) {
            int p = atomicAdd(&deg[d.z], 1);
            if (p < CSR_STRIDE)
                csr[d.z * CSR_STRIDE + p] = __builtin_nontemporal_load(ei + e0 + 2);
        }
        if (d.w >= lo && d.w < hi) {
            int p = atomicAdd(&deg[d.w], 1);
            if (p < CSR_STRIDE)
                csr[d.w * CSR_STRIDE + p] = __builtin_nontemporal_load(ei + e0 + 3);
        }
    }
}

// ---- fused GIN layer v9: v5 paired gather + MFMA bf16 MLP (fp32 accum).
// v7/v8 split regressed (+17us traffic); reverted to fused. MLP: per wave a
// 16-row block x 4 col-blocks, mfma_f32_16x16x32_bf16, K=64 = 2 steps.
// LDS bf16: asb[128][72] (agg/z/h; eidx staged in bytes 0..127 of each row,
// overwritten per-row after its reads complete -- data-dep-safe, v5-proven),
// wsb[64][72] = W^T so B-frags are contiguous 16 B. 28 KB total (was 52.7).
// A-frag: lane(row=l&15, k=8*(l>>4)+e); B-frag: lane(col=l&15, same k);
// C/D: col=l&15, row=4*(l>>4)+reg (HW-verified mapping).
__global__ __launch_bounds__(512, 6) void gather_mlp_kernel(
    const uint2* __restrict__ hin, uint2* __restrict__ hout,
    const int* __restrict__ csr, const int* __restrict__ deg,
    const float* __restrict__ W1, const float* __restrict__ b1,
    const float* __restrict__ W2, const float* __restrict__ b2)
{
    __shared__ unsigned short asb[BLK_N][APITCH];  // agg/z/h bf16 (+eidx overlap)
    __shared__ unsigned short wsb[N_HID][APITCH];  // W^T bf16 [n][k]
    __shared__ int sdeg[BLK_N];
    const int tid = threadIdx.x;
    const int tx = tid & 15, ty = tid >> 4;   // ty = gather group 0..31
    const int sub = tx;
    const int n0 = blockIdx.x * BLK_N;

    // stage W1^T bf16 (coalesced global read, 2-way-bank LDS scatter)
#pragma unroll
    for (int t = 0; t < 8; ++t) {
        const int idx = t * 512 + tid;        // 0..4095: k=idx>>6, n=idx&63
        wsb[idx & 63][idx >> 6] = (unsigned short)bf_rne(W1[idx]);
    }
    if (tid < BLK_N) {
        const int node = n0 + tid;
        sdeg[tid] = (node < N_NODES) ? deg[node] : 0;
    }
    // stage edge indices: 32 ints into bytes [0..128) of each asb row
#pragma unroll
    for (int t = 0; t < 2; ++t) {
        const int idx = t * 512 + tid;        // 0..1023 int4 slots
        const int r = idx >> 3, s4 = idx & 7;
        const int node = n0 + r;
        int4 v = make_int4(0, 0, 0, 0);
        if (node < N_NODES)
            v = *(const int4*)(csr + (size_t)node * CSR_STRIDE + s4 * 4);
        *(int4*)((char*)&asb[r][0] + s4 * 16) = v;
    }
    __syncthreads();

    // gather: group ty owns rows ty, ty+32, ty+64, ty+96; pairs (rA, rB=rA+32),
    // 16 row-loads in flight per group (v5, +4us vs serial rows).
    for (int pp = 0; pp < 2; ++pp) {
        const int rA = ty + 64 * pp;
        const int rB = rA + 32;
        const int nodeA = n0 + rA;
        const int nodeB = n0 + rB;
        float aAx = 0.f, aAy = 0.f, aAz = 0.f, aAw = 0.f;
        float bAx = 0.f, bAy = 0.f, bAz = 0.f, bAw = 0.f;
        float aBx = 0.f, aBy = 0.f, aBz = 0.f, aBw = 0.f;
        float bBx = 0.f, bBy = 0.f, bBz = 0.f, bBw = 0.f;
        int nA = 0, nB = 0;
        if (nodeA < N_NODES) {
            nA = sdeg[rA]; nA = nA > CSR_STRIDE ? CSR_STRIDE : nA;
            const uint2 s = hin[(size_t)nodeA * 16 + sub];   // self term
            aAx = bflo(s.x); aAy = bfhi(s.x); aAz = bflo(s.y); aAw = bfhi(s.y);
        }
        if (nodeB < N_NODES) {
            nB = sdeg[rB]; nB = nB > CSR_STRIDE ? CSR_STRIDE : nB;
            const uint2 s = hin[(size_t)nodeB * 16 + sub];   // self term
            aBx = bflo(s.x); aBy = bfhi(s.x); aBz = bflo(s.y); aBw = bfhi(s.y);
        }
        const int nnA = nA > EMAX_LDS ? EMAX_LDS : nA;
        const int nnB = nB > EMAX_LDS ? EMAX_LDS : nB;
        const int* epA = (const int*)&asb[rA][0];
        const int* epB = (const int*)&asb[rB][0];
        const int mx = nnA > nnB ? nnA : nnB;
        for (int eb = 0; eb < mx; eb += 8) {
            uint2 rvA[8], rvB[8];
            const bool doA = eb < nnA;
            const bool doB = eb < nnB;
            if (doA) {
#pragma unroll
                for (int u = 0; u < 8; ++u) {
                    const int idx = eb + u;
                    const int cl = idx < nnA ? idx : nnA - 1;  // clamp: slots>=deg poison
                    rvA[u] = hin[(size_t)epA[cl] * 16 + sub];
                }
            }
            if (doB) {
#pragma unroll
                for (int u = 0; u < 8; ++u) {
                    const int idx = eb + u;
                    const int cl = idx < nnB ? idx : nnB - 1;
                    rvB[u] = hin[(size_t)epB[cl] * 16 + sub];
                }
            }
            if (doA) {
#pragma unroll
                for (int u = 0; u < 8; u += 2) {
                    if (eb + u < nnA) {
                        aAx += bflo(rvA[u].x); aAy += bfhi(rvA[u].x);
                        aAz += bflo(rvA[u].y); aAw += bfhi(rvA[u].y);
                    }
                    if (eb + u + 1 < nnA) {
                        bAx += bflo(rvA[u + 1].x); bAy += bfhi(rvA[u + 1].x);
                        bAz += bflo(rvA[u + 1].y); bAw += bfhi(rvA[u + 1].y);
                    }
                }
            }
            if (doB) {
#pragma unroll
                for (int u = 0; u < 8; u += 2) {
                    if (eb + u < nnB) {
                        aBx += bflo(rvB[u].x); aBy += bfhi(rvB[u].x);
                        aBz += bflo(rvB[u].y); aBw += bfhi(rvB[u].y);
                    }
                    if (eb + u + 1 < nnB) {
                        bBx += bflo(rvB[u + 1].x); bBy += bfhi(rvB[u + 1].x);
                        bBz += bflo(rvB[u + 1].y); bBw += bfhi(rvB[u + 1].y);
                    }
                }
            }
        }
        for (int t = EMAX_LDS; t < nA; ++t) { // rare tail (P~1e-4)
            const int s0 = csr[(size_t)nodeA * CSR_STRIDE + t];
            const uint2 a = hin[(size_t)s0 * 16 + sub];
            aAx += bflo(a.x); aAy += bfhi(a.x);
            aAz += bflo(a.y); aAw += bfhi(a.y);
        }
        for (int t = EMAX_LDS; t < nB; ++t) {
            const int s0 = csr[(size_t)nodeB * CSR_STRIDE + t];
            const uint2 a = hin[(size_t)s0 * 16 + sub];
            aBx += bflo(a.x); aBy += bfhi(a.x);
            aBz += bflo(a.y); aBw += bfhi(a.y);
        }
        // write agg rows bf16 (overwrites this row's eidx bytes -- all eidx
        // reads of this row completed by data dependency). Invalid rows = 0.
        *(uint2*)((char*)&asb[rA][0] + sub * 8) = make_uint2(
            pack2(aAx + bAx, aAy + bAy), pack2(aAz + bAz, aAw + bAw));
        *(uint2*)((char*)&asb[rB][0] + sub * 8) = make_uint2(
            pack2(aBx + bBx, aBy + bBy), pack2(aBz + bBz, aBw + bBw));
    }
    __syncthreads();

    // ---- MFMA MLP ----
    const int wave = tid >> 6;            // row-block 0..7 (rows wave*16..+16)
    const int lane = tid & 63;
    const int lr = lane & 15;
    const int lg = lane >> 4;
    const f32x4 vzero = {0.f, 0.f, 0.f, 0.f};

    // GEMM1: z = relu(agg @ W1 + b1)
    f32x4 acc[4] = {vzero, vzero, vzero, vzero};
    {
        const char* ar = (const char*)&asb[wave * 16 + lr][0] + lg * 16;
        const bf16x8 a0 = *(const bf16x8*)ar;
        const bf16x8 a1 = *(const bf16x8*)(ar + 64);
#pragma unroll
        for (int cb = 0; cb < 4; ++cb) {
            const char* br = (const char*)&wsb[cb * 16 + lr][0] + lg * 16;
            const bf16x8 w0 = *(const bf16x8*)br;
            const bf16x8 w1 = *(const bf16x8*)(br + 64);
            acc[cb] = __builtin_amdgcn_mfma_f32_16x16x32_bf16(a0, w0, acc[cb], 0, 0, 0);
            acc[cb] = __builtin_amdgcn_mfma_f32_16x16x32_bf16(a1, w1, acc[cb], 0, 0, 0);
        }
    }
#pragma unroll
    for (int cb = 0; cb < 4; ++cb) {
        const float bias = b1[cb * 16 + lr];
#pragma unroll
        for (int rg = 0; rg < 4; ++rg) {
            const float v = fmaxf(acc[cb][rg] + bias, 0.f);
            asb[wave * 16 + lg * 4 + rg][cb * 16 + lr] = (unsigned short)bf_rne(v);
        }
    }
    __syncthreads();                       // all W1 B-frag reads done
#pragma unroll
    for (int t = 0; t < 8; ++t) {
        const int idx = t * 512 + tid;
        wsb[idx & 63][idx >> 6] = (unsigned short)bf_rne(W2[idx]);
    }
    __syncthreads();

    // GEMM2: h = relu(z @ W2 + b2)
#pragma unroll
    for (int cb = 0; cb < 4; ++cb) acc[cb] = vzero;
    {
        const char* ar = (const char*)&asb[wave * 16 + lr][0] + lg * 16;
        const bf16x8 a0 = *(const bf16x8*)ar;
        const bf16x8 a1 = *(const bf16x8*)(ar + 64);
#pragma unroll
        for (int cb = 0; cb < 4; ++cb) {
            const char* br = (const char*)&wsb[cb * 16 + lr][0] + lg * 16;
            const bf16x8 w0 = *(const bf16x8*)br;
            const bf16x8 w1 = *(const bf16x8*)(br + 64);
            acc[cb] = __builtin_amdgcn_mfma_f32_16x16x32_bf16(a0, w0, acc[cb], 0, 0, 0);
            acc[cb] = __builtin_amdgcn_mfma_f32_16x16x32_bf16(a1, w1, acc[cb], 0, 0, 0);
        }
    }
#pragma unroll
    for (int cb = 0; cb < 4; ++cb) {
        const float bias = b2[cb * 16 + lr];
#pragma unroll
        for (int rg = 0; rg < 4; ++rg) {
            const float v = fmaxf(acc[cb][rg] + bias, 0.f);
            asb[wave * 16 + lg * 4 + rg][cb * 16 + lr] = (unsigned short)bf_rne(v);
        }
    }
    __syncthreads();

    // coalesced copy-out (uint2 per lane)
#pragma unroll
    for (int t = 0; t < 4; ++t) {
        const int idx = t * 512 + tid;        // 0..2047
        const int m = idx >> 4, kv = idx & 15;
        if (n0 + m < N_NODES)
            hout[(size_t)(n0 + m) * 16 + kv] =
                *(const uint2*)((const char*)&asb[m][0] + kv * 8);
    }
}

// ---- fused pool+head: block per graph; wave 0 finishes post/ro/log_softmax
// in-register from the pooled row. h is bf16. ----
__global__ __launch_bounds__(256) void pool_head_kernel(
    const unsigned short* __restrict__ h, const int* __restrict__ batch,
    const float* __restrict__ Wp, const float* __restrict__ bp,
    const float* __restrict__ Wr, const float* __restrict__ br,
    float* __restrict__ out)
{
    const int graph = blockIdx.x;
    int l = 0, r = N_NODES;
    while (l < r) { int m = (l + r) >> 1; if (batch[m] < graph) l = m + 1; else r = m; }
    const int lo = l;
    r = N_NODES;
    while (l < r) { int m = (l + r) >> 1; if (batch[m] < graph + 1) l = m + 1; else r = m; }
    const int hi = l;

    const int lane = threadIdx.x & 63;
    const int wave = threadIdx.x >> 6;
    float acc = 0.0f;
    for (int i = lo + wave; i < hi; i += 4)
        acc += __uint_as_float(((unsigned)h[(size_t)i * N_HID + lane]) << 16);
    __shared__ float sacc[4][N_HID];
    sacc[wave][lane] = acc;
    __syncthreads();
    if (wave != 0) return;

    const float gv = sacc[0][lane] + sacc[1][lane] + sacc[2][lane] + sacc[3][lane];
    float acc2 = bp[lane];
#pragma unroll
    for (int k = 0; k < N_HID; ++k) {
        const float gk = __int_as_float(
            __builtin_amdgcn_readlane(__float_as_int(gv), k));
        acc2 = fmaf(gk, Wp[k * N_HID + lane], acc2);
    }
    const float y = fmaxf(acc2, 0.f);

    float logit = (lane < N_CLASS) ? br[lane] : 0.f;
#pragma unroll
    for (int k = 0; k < N_HID; ++k) {
        const float yk = __int_as_float(
            __builtin_amdgcn_readlane(__float_as_int(y), k));
        if (lane < N_CLASS)
            logit = fmaf(yk, Wr[k * N_CLASS + lane], logit);
    }

    __shared__ float slog[N_CLASS];
    if (lane < N_CLASS) slog[lane] = logit;
    if (lane < N_CLASS) {
        float m = -INFINITY;
#pragma unroll
        for (int c = 0; c < N_CLASS; ++c) m = fmaxf(m, slog[c]);
        float sum = 0.0f;
#pragma unroll
        for (int c = 0; c < N_CLASS; ++c) sum += expf(slog[c] - m);
        out[(size_t)graph * N_CLASS + lane] = logit - m - logf(sum);
    }
}

extern "C" void kernel_launch(void* const* d_in, const int* in_sizes, int n_in,
                              void* d_out, int out_size, void* d_ws, size_t ws_size,
                              hipStream_t stream)
{
    const float* x       = (const float*)d_in[0];
    const int*   ei      = (const int*)d_in[1];   // [2, E]: row0=src, row1=dst
    const int*   batch   = (const int*)d_in[2];
    const float* pre_w   = (const float*)d_in[3];
    const float* pre_b   = (const float*)d_in[4];
    const float* conv_w1 = (const float*)d_in[5];
    const float* conv_b1 = (const float*)d_in[6];
    const float* conv_w2 = (const float*)d_in[7];
    const float* conv_b2 = (const float*)d_in[8];
    const float* post_w  = (const float*)d_in[9];
    const float* post_b  = (const float*)d_in[10];
    const float* ro_w    = (const float*)d_in[11];
    const float* ro_b    = (const float*)d_in[12];
    float* out = (float*)d_out;

    // workspace layout (~51.6 MB)
    uint2* h0   = (uint2*)d_ws;                       // 12.8 MB (bf16 h)
    uint2* h1   = h0 + (size_t)N_NODES * 16;          // 12.8 MB
    int*   deg  = (int*)(h1 + (size_t)N_NODES * 16);  // 400 KB
    int*   csr  = deg + N_NODES;                      // 25.6 MB fixed-stride

    (void)hipMemsetAsync(deg, 0, N_NODES * sizeof(int), stream);

    pre_kernel<<<NTILES, 256, 0, stream>>>(x, pre_w, pre_b, h0);
    hist_fill_kernel<<<HF_BLOCKS, 256, 0, stream>>>(ei, deg, csr);

    // 3 fused GIN layers, h ping-pong h0 -> h1 -> h0 -> h1
    gather_mlp_kernel<<<NT2, 512, 0, stream>>>(
        h0, h1, csr, deg,
        conv_w1, conv_b1, conv_w2, conv_b2);
    gather_mlp_kernel<<<NT2, 512, 0, stream>>>(
        h1, h0, csr, deg,
        conv_w1 + N_HID * N_HID, conv_b1 + N_HID,
        conv_w2 + N_HID * N_HID, conv_b2 + N_HID);
    gather_mlp_kernel<<<NT2, 512, 0, stream>>>(
        h0, h1, csr, deg,
        conv_w1 + 2 * N_HID * N_HID, conv_b1 + 2 * N_HID,
        conv_w2 + 2 * N_HID * N_HID, conv_b2 + 2 * N_HID);

    pool_head_kernel<<<N_GRAPHS, 256, 0, stream>>>(
        (const unsigned short*)h1, batch, post_w, post_b, ro_w, ro_b, out);
}